// Round 14
// baseline (311.098 us; speedup 1.0000x reference)
//
#include <hip/hip_runtime.h>

// DynamicFilter: out[b,c,h,w] = sum_p (y[c*9+p] + bias[c*9+p]) * x[b,c,h+dh,w+dw]
//   y[o] = sum_c' x[b,c',h,w] * W[o,c']   (GEMM M=65536, N=2304, K=256, bf16 MFMA)
// B=4, C=256, H=W=128, 9 taps.
// R12 125us (ppw16: 16 w/CU but 2x LDS traffic = 93us wall). R15 126us
//   (ppw32: LDS 46us but only 2048 waves EXIST = 8/CU; all pipes <=37%).
// Invariant: total LDS reads = waves x chunks-each x 73728 -> splitting the
//   CHUNK dim across blocks adds waves at constant LDS traffic.
// R16: grid 1024 = 512 row-blocks x 2 chunk-halves (8 chunks each) -> 4096
//   waves; ring-4 (49152 B) -> 3 blocks/CU -> 12 waves/CU (3/SIMD, +50%
//   hiding). launch_bounds(256,3): cap 170 >= need ~130 (not R7's trap).
//   Schedule: R14's per-phase skeleton, distance-3: phase j {SYNC; stage sub
//   j+3 -> buf (S+3)&3; GEMM sub j from buf S&3}. Phase read-buf vs stage-buf
//   always differ by 3 (mod 4); WAR = prior reads drained by each SYNC's
//   lgkm+barrier. Waits (audited): j=0 VM(8) (subs 0-2 force-retired by the
//   epilogue's consumed patch loads; only <=8 stores fly), j=1 VM(11),
//   j=2 VM(14) (depth bounds), j=3..5 VM(6) (exactly the 2 newer stages).
//   Cost: afr x-row loads x2 (+64 MB FETCH at 25%-busy HBM).

typedef __attribute__((ext_vector_type(8))) short bf16x8;   // 8 bf16 = 4 VGPRs
typedef __attribute__((ext_vector_type(4))) float f32x4;    // MFMA 16x16 acc

__device__ __forceinline__ unsigned int f2bf(float f) {
    unsigned int u = __float_as_uint(f);
    return (u + 0x7fffu + ((u >> 16) & 1u)) >> 16;   // RNE
}
__device__ __forceinline__ unsigned int pack2(float a, float b) {
    return f2bf(a) | (f2bf(b) << 16);
}

// ---------------------------------------------------------------------------
// Kernel 1: W (2304x256 fp32) -> Wb bf16, instruction-ordered A-fragments
// with channel-aligned out permutation (unchanged from R11..R15):
//   o: chunk=o/144, oc=o%144, c_local=oc/9, p=oc%9
//   q=c_local/4, c4=c_local%4, idx=c4*9+p, ni=idx/4, j=idx%4, r=q*4+j
//   k: kh=k/128, s=(k%128)/32, kq=(k%32)/8, e=k%8; jsub=kh*3+ni/3; ni_=ni%3
//   dst = chunk*73728 + jsub*12288 + (s*3+ni_)*1024 + (kq*16+r)*16 + e*2
// ---------------------------------------------------------------------------
__global__ __launch_bounds__(256) void wconv_kernel(const float* __restrict__ W,
                                                    unsigned char* __restrict__ Wb) {
    int idx0 = blockIdx.x * 256 + threadIdx.x;   // 73728 = 2304 * 32 groups
    int o = idx0 >> 5, g = idx0 & 31;
    const float4* src = (const float4*)(W + ((size_t)o << 8) + ((size_t)g << 3));
    float4 v0 = src[0], v1 = src[1];
    uint4 pk;
    pk.x = pack2(v0.x, v0.y); pk.y = pack2(v0.z, v0.w);
    pk.z = pack2(v1.x, v1.y); pk.w = pack2(v1.z, v1.w);
    int kh = g >> 4, g2 = g & 15, s = g2 >> 2, kq = g2 & 3;
    int chunk = o / 144, oc = o - chunk * 144;
    int c_local = oc / 9, p = oc - c_local * 9;
    int q = c_local >> 2, c4 = c_local & 3;
    int idx = c4 * 9 + p;
    int ni = idx >> 2, j = idx & 3, r = (q << 2) + j;
    int jsub = kh * 3 + ni / 3, ni_ = ni % 3;
    size_t dst = (size_t)chunk * 73728 + (size_t)jsub * 12288
               + (size_t)(s * 3 + ni_) * 1024 + (size_t)((kq << 4) + r) * 16;
    *(uint4*)(Wb + dst) = pk;
}

// ---------------------------------------------------------------------------
// Kernel 2. LDS: ring-4 bufs at buf*12288, total 49152 B -> 3 blocks/CU.
// Block = (row, chunk-half). Sub index S = lc*6 + j (lc = local chunk 0..7);
// buf = S & 3. 4 waves x 32 px (2 mi halves) = 128-px row.
// ---------------------------------------------------------------------------

#define SYNC_VM(N) asm volatile("s_waitcnt vmcnt(" #N ") lgkmcnt(0)\n\ts_barrier" ::: "memory")
#define FENCE      asm volatile("" ::: "memory")   // compile-time order pin only

// Stage sub-tile J (0..5) of chunk CH into ring buf BUF (runtime). Wave wv
// stages 3072 B as 3 x global_load_lds(16B). Per-wave vmcnt += 3.
#define STAGE(CH, J, BUF)                                                       \
    do {                                                                        \
        const unsigned char* bs_ = Wb + (size_t)(CH) * 73728                    \
            + (size_t)(J) * 12288 + wv * 3072 + (lane << 4);                    \
        unsigned char* bd_ = smem + (size_t)(BUF) * 12288 + wv * 3072;          \
        _Pragma("unroll")                                                       \
        for (int c_ = 0; c_ < 3; ++c_)                                          \
            __builtin_amdgcn_global_load_lds(                                   \
                (const __attribute__((address_space(1))) void*)(bs_ + c_ * 1024), \
                (__attribute__((address_space(3))) void*)(bd_ + c_ * 1024), 16, 0, 0); \
    } while (0)

// 24 MFMAs on sub-tile J (3 ni x 4 s x 2 mi) sharing 12 ds_read_b128 (each
// bq feeds both mi halves). J compile-time (kh/snib), BUF runtime.
// acc[mi][ni] = C[out_row][px_col]: col=lane&15=px, row=quad*4+reg=out-slot.
#define MFMA_SUB(J, BUF)                                                        \
    do {                                                                        \
        const int kh_ = (J) / 3, snib_ = ((J) % 3) * 3;                         \
        const unsigned char* bb_ = smem + (size_t)(BUF) * 12288 + (lane << 4);  \
        _Pragma("unroll")                                                       \
        for (int s_ = 0; s_ < 4; ++s_) {                                        \
            const bf16x8 a0_ = afr[(kh_ << 2) + s_];                            \
            const bf16x8 a1_ = afr[8 + (kh_ << 2) + s_];                        \
            _Pragma("unroll")                                                   \
            for (int ni_ = 0; ni_ < 3; ++ni_) {                                 \
                const bf16x8 bq_ = *(const bf16x8*)(bb_ + ((s_ * 3 + ni_) << 10)); \
                acc[0][snib_ + ni_] = __builtin_amdgcn_mfma_f32_16x16x32_bf16(  \
                    bq_, a0_, acc[0][snib_ + ni_], 0, 0, 0);                    \
                acc[1][snib_ + ni_] = __builtin_amdgcn_mfma_f32_16x16x32_bf16(  \
                    bq_, a1_, acc[1][snib_ + ni_], 0, 0, 0);                    \
            }                                                                   \
        }                                                                       \
    } while (0)

__global__ __launch_bounds__(256, 3) void dfgemm_kernel(
        const unsigned char* __restrict__ Wb, const float* __restrict__ x,
        const float* __restrict__ bias, float* __restrict__ out) {
    __shared__ __align__(16) unsigned char smem[49152];

    const int t = threadIdx.x;
    const int lane = t & 63, wv = t >> 6;        // wv 0..3
    const int quad = lane >> 4, lrow = lane & 15;

    const int half = blockIdx.x & 1;             // chunk half (adjacent bids
    const int rowid = blockIdx.x >> 1;           //  share a row -> L2 reuse)
    const int b = rowid >> 7;                    // image 0..3
    const int h = rowid & 127;                   // row
    const int c0 = half << 3;                    // first chunk of this half

    // Prologue: stage subs 0,1,2 of chunk c0 into bufs 0,1,2.
    STAGE(c0, 0, 0); STAGE(c0, 1, 1); STAGE(c0, 2, 2);

    // ---- A(pixel) fragments: afr[mi*8+kh*4+s][e] = bf16(x[b, ch, h, w]) ----
    bf16x8 afr[16];
    {
        const float* xrow = x + ((size_t)b << 22) + (h << 7);
        #pragma unroll
        for (int mi = 0; mi < 2; ++mi) {
            const int w = (wv << 5) + (mi << 4) + lrow;
            #pragma unroll
            for (int gg = 0; gg < 8; ++gg) {
                const float* p = xrow + ((size_t)((gg << 5) + (quad << 3)) << 14) + w;
                float v[8];
                #pragma unroll
                for (int e = 0; e < 8; ++e) v[e] = p[(size_t)e << 14];
                uint4 pk;
                pk.x = pack2(v[0], v[1]); pk.y = pack2(v[2], v[3]);
                pk.z = pack2(v[4], v[5]); pk.w = pack2(v[6], v[7]);
                afr[(mi << 3) + gg] = *(const bf16x8*)&pk;
            }
        }
    }
    SYNC_VM(0);                        // prologue only: subs 0-2 landed, full drain

    #pragma unroll 1
    for (int lc = 0; lc < 8; ++lc) {
        const int chunk = c0 + lc;
        const int cnext = c0 + ((lc + 1) & 7);   // tail wraps: harmless re-stage
        const int bb0 = (lc * 6) & 3;            // buf of this chunk's sub 0
        f32x4 acc[2][9];
        const f32x4 zero = {0.f, 0.f, 0.f, 0.f};
        #pragma unroll
        for (int mi = 0; mi < 2; ++mi)
            #pragma unroll
            for (int ni = 0; ni < 9; ++ni) acc[mi][ni] = zero;

        // j=0: subs 0-2 (staged 3+ phases ago) force-retired by the prior
        // epilogue's consumed patch loads; VM(8) bounds the <=8 stores.
        SYNC_VM(8);
        STAGE(chunk, 3, (bb0 + 3) & 3);
        MFMA_SUB(0, bb0);

        SYNC_VM(11);                           // j=1: depth bound (stores + 1 stage)
        STAGE(chunk, 4, (bb0 + 4) & 3);
        MFMA_SUB(1, (bb0 + 1) & 3);

        SYNC_VM(14);                           // j=2: depth bound (stores + 2 stages)
        STAGE(chunk, 5, (bb0 + 5) & 3);
        MFMA_SUB(2, (bb0 + 2) & 3);

        SYNC_VM(6);                            // j=3: retire sub3 (staged j=0);
        STAGE(cnext, 0, (bb0 + 6) & 3);        //      2 newer stages keep flying
        MFMA_SUB(3, (bb0 + 3) & 3);

        SYNC_VM(6);                            // j=4: retire sub4 (staged j=1)
        STAGE(cnext, 1, (bb0 + 7) & 3);
        MFMA_SUB(4, (bb0 + 4) & 3);

        SYNC_VM(6);                            // j=5: retire sub5 (staged j=2)
        STAGE(cnext, 2, (bb0 + 8) & 3);
        MFMA_SUB(5, (bb0 + 5) & 3);
        FENCE;                                 // pin stages BEFORE epi patch loads

        // ---- epilogue: pure-register. Lane owns pixels w(mi) and 4 whole
        //      channels (quad*4+c4); acc slot for (c4,p): idx=c4*9+p,
        //      ni=idx/4, j=idx%4 -- all compile-time. No LDS. ----
        #pragma unroll
        for (int mi = 0; mi < 2; ++mi) {
            const int w = (wv << 5) + (mi << 4) + lrow;      // this lane's pixel
            #pragma unroll
            for (int c4 = 0; c4 < 4; ++c4) {
                const int cg = (chunk << 4) + (quad << 2) + c4;  // channel
                const float* bp = bias + cg * 9;
                const float* xc = x + ((size_t)((b << 8) + cg) << 14);
                float sum = 0.f;
                #pragma unroll
                for (int p = 0; p < 9; ++p) {
                    const int idx = c4 * 9 + p;
                    const int ni = idx >> 2, j = idx & 3;
                    const float yv = acc[mi][ni][j];
                    const int hh = h + p / 3 - 1, ww = w + p % 3 - 1;
                    float xv = 0.f;
                    if ((unsigned)hh < 128u && (unsigned)ww < 128u)
                        xv = xc[(hh << 7) + ww];             // fp32 patch
                    sum += (yv + bp[p]) * xv;
                }
                out[((size_t)((b << 8) + cg) << 14) + (h << 7) + w] = sum;
            }
        }
    }
}

extern "C" void kernel_launch(void* const* d_in, const int* in_sizes, int n_in,
                              void* d_out, int out_size, void* d_ws, size_t ws_size,
                              hipStream_t stream) {
    const float* x    = (const float*)d_in[0];   // 4*256*128*128
    const float* W    = (const float*)d_in[1];   // 2304*256
    const float* bias = (const float*)d_in[2];   // 2304
    float* out = (float*)d_out;

    unsigned char* Wb = (unsigned char*)d_ws;    // 1,179,648 B

    wconv_kernel<<<288, 256, 0, stream>>>(W, Wb);
    dfgemm_kernel<<<1024, 256, 0, stream>>>(Wb, x, bias, out);
}